// Round 2
// baseline (4681.672 us; speedup 1.0000x reference)
//
#include <hip/hip_runtime.h>
#include <stdint.h>

// ====== variant switches for XLA:CPU transcendental reconstruction ======
// (verified bit-exact in round 1 — DO NOT change the math)
#define XLA_LOG_TAIL_A 1
#define XLA_USE_FMA    0

#if XLA_USE_FMA
#define MADD(a,b,c) __builtin_fmaf((a),(b),(c))
#else
#define MADD(a,b,c) ((a)*(b)+(c))
#endif

#define N_NEUR 2048
#define HALF_N 1024

// ---------------- threefry2x32 (exact JAX primitive) ----------------
__device__ __forceinline__ uint32_t rotl32(uint32_t x, int r) {
  return (x << r) | (x >> (32 - r));
}

__device__ __forceinline__ void tf2x32(uint32_t k0, uint32_t k1,
                                       uint32_t& x0, uint32_t& x1) {
  const uint32_t k2 = k0 ^ k1 ^ 0x1BD11BDAu;
  x0 += k0; x1 += k1;
#define TF_R(r) { x0 += x1; x1 = rotl32(x1, r); x1 ^= x0; }
  TF_R(13) TF_R(15) TF_R(26) TF_R(6)
  x0 += k1; x1 += k2 + 1u;
  TF_R(17) TF_R(29) TF_R(16) TF_R(24)
  x0 += k2; x1 += k0 + 2u;
  TF_R(13) TF_R(15) TF_R(26) TF_R(6)
  x0 += k0; x1 += k1 + 3u;
  TF_R(17) TF_R(29) TF_R(16) TF_R(24)
  x0 += k1; x1 += k2 + 4u;
  TF_R(13) TF_R(15) TF_R(26) TF_R(6)
  x0 += k2; x1 += k0 + 5u;
#undef TF_R
}

__device__ __forceinline__ float u01_from_bits(uint32_t bits) {
#pragma clang fp contract(off)
  float f = __uint_as_float((bits >> 9) | 0x3f800000u);
  return f - 1.0f;
}

// ---------------- XLA:CPU GenerateVF32Log (Cephes, Estrin poly) ----------------
__device__ __forceinline__ float xla_log(float xin) {
#pragma clang fp contract(off)
  float t0 = fmaxf(xin, __uint_as_float(0x00800000u));
  uint32_t bits = __float_as_uint(t0);
  int em = (int)(bits >> 23) - 127;
  t0 = __uint_as_float((bits & 0x807fffffu) | 0x3f000000u);
  float e = 1.0f + (float)em;
  const bool mlt = t0 < (float)0.707106781186547524;
  float tmp1 = mlt ? t0 : 0.0f;
  t0 = t0 - 1.0f;
  e = e - (mlt ? 1.0f : 0.0f);
  t0 = t0 + tmp1;
  float x2 = t0 * t0;
  float x3 = x2 * t0;
  float y  = MADD(t0, (float)7.0376836292E-2, (float)-1.1514610310E-1);
  float ya = MADD(t0, (float)-1.2420140846E-1, (float)1.4249322787E-1);
  float yb = MADD(t0, (float)2.0000714765E-1, (float)-2.4999993993E-1);
  y  = MADD(y,  t0, (float)1.1676998740E-1);
  ya = MADD(ya, t0, (float)-1.6668057665E-1);
  yb = MADD(yb, t0, (float)3.3333331174E-1);
  y  = MADD(y, x3, ya);
  y  = MADD(y, x3, yb);
  y  = y * x3;
  float ey1 = e * (float)-2.12194440e-4;
  float hx2 = x2 * 0.5f;
  y = y + ey1;
  t0 = t0 - hx2;
  float ey2 = e * (float)0.693359375;
#if XLA_LOG_TAIL_A
  t0 = t0 + y;
  t0 = t0 + ey2;
#else
  t0 = t0 + ey2;
  t0 = t0 + y;
#endif
  if (xin == 0.0f) return -__builtin_inff();
  return t0;
}

// ---------------- XLA:CPU GenerateVF32Exp (old Cephes structure) ----------------
__device__ __forceinline__ float xla_exp(float xin) {
#pragma clang fp contract(off)
  float x = fmaxf(xin, (float)-88.3762626647949);
  x = fminf(x, (float)88.3762626647950);
  float fx = floorf(MADD(x, (float)1.44269504088896341, 0.5f));
  float tmp = (float)0.693359375 * fx;
  float z = (float)-2.12194440e-4 * fx;
  x = x - tmp;
  x = x - z;
  z = x * x;
  float y = MADD(x, (float)1.9875691500E-4, (float)1.3981999507E-3);
  y = MADD(y, x, (float)8.3334519073E-3);
  y = MADD(y, x, (float)4.1665795894E-2);
  y = MADD(y, x, (float)1.6666665459E-1);
  y = MADD(y, x, (float)5.0000001201E-1);
  y = MADD(y, z, x);
  y = 1.0f + y;
  int n = (int)fx;
  float p2n = __uint_as_float((uint32_t)(n + 127) << 23);
  return fmaxf(y * p2n, xin);
}

__device__ __forceinline__ float xla_log1p(float x) {
#pragma clang fp contract(off)
  float fl = xla_log(x + 1.0f);
  float fs = ((-0.5f * x) + 1.0f) * x;
  return (fabsf(x) < (float)1e-4) ? fs : fl;
}

// jax.nn.softplus(v) = max(v,0) + log1p(exp(-|v|))
__device__ __forceinline__ float softplus_xla(float v) {
#pragma clang fp contract(off)
  // exact shortcut: for v>=16, exp(-v)<=1.13e-7 < ulp(v)/2 -> sum rounds to v
  if (v >= 16.0f) return v;
  float a = fabsf(v);
  float ex = xla_exp(-a);
  float lp = xla_log1p(ex);
  return fmaxf(v, 0.0f) + lp;
}

// ---------------- init: tevents/yevents = +inf, event_types = 0 ----------------
__global__ void snn_init(float* __restrict__ out, size_t inf_base,
                         size_t inf_cnt, size_t zero_cnt) {
  size_t i = (size_t)blockIdx.x * blockDim.x + threadIdx.x;
  size_t stride = (size_t)gridDim.x * blockDim.x;
  size_t total = inf_cnt + zero_cnt;
  for (size_t k = i; k < total; k += stride) {
    out[inf_base + k] = (k < inf_cnt) ? __builtin_inff() : 0.0f;
  }
}

// ---------------- precompute s_reset[step][j] = log(u)-alpha into d_ws ---------
__global__ __launch_bounds__(1024)
void snn_pre(const int* __restrict__ seedp, float* __restrict__ sres) {
#pragma clang fp contract(off)
  const int step = blockIdx.x;       // 0..T-2
  const int t = threadIdx.x;
  uint32_t seed = (uint32_t)seedp[0];
  uint32_t a0 = 0u, a1 = 2u; tf2x32(0u, seed, a0, a1);
  uint32_t b0 = 1u, b1 = 3u; tf2x32(0u, seed, b0, b1);
  uint32_t f0 = 0u, f1 = (uint32_t)step; tf2x32(a1, b1, f0, f1);
  uint32_t d0 = (uint32_t)t, d1 = (uint32_t)(t + HALF_N);
  tf2x32(f0, f1, d0, d1);
  float srA = xla_log(u01_from_bits(d0)) - 0.01f;
  float srB = xla_log(u01_from_bits(d1)) - 0.01f;
  sres[(size_t)step * N_NEUR + t] = srA;
  sres[(size_t)step * N_NEUR + HALF_N + t] = srB;
}

// ---------------- the sequential scan: 1 block, 512 threads, 4 neurons each ----
__global__ __launch_bounds__(512, 1)
void snn_sim(const float* __restrict__ ts, const float* __restrict__ v0,
             const float* __restrict__ i0, const float* __restrict__ ic,
             const float* __restrict__ w, const float* __restrict__ mu,
             const int* __restrict__ seedp, const float* __restrict__ sres,
             float* __restrict__ out, int T, int MS) {
#pragma clang fp contract(off)
  const int t = threadIdx.x;
  const int nb = t * 4;                 // 4 contiguous neurons nb..nb+3

  float* ys   = out;                                     // [T][N][3]
  float* tev  = out + (size_t)T * N_NEUR * 3;            // [MS]
  float* yev  = tev + (size_t)MS;                        // [MS][N][3]
  float* etv  = yev + (size_t)MS * N_NEUR * 3;           // [MS][N]
  float* nspp = etv + (size_t)MS * N_NEUR;               // [1]

  // keys: key=(0,seed); split -> k_init (first cipher words), k_trans (second)
  uint32_t seed = (uint32_t)seedp[0];
  uint32_t a0 = 0u, a1 = 2u; tf2x32(0u, seed, a0, a1);
  uint32_t b0 = 1u, b1 = 3u; tf2x32(0u, seed, b0, b1);
  const uint32_t ki0 = a0, ki1 = b0;   // k_init
  const uint32_t kt0 = a1, kt1 = b1;   // k_trans

  float v[4], cur[4], s[4], icr[4];
  {
    float4 vv = *(const float4*)&v0[nb];
    float4 ii = *(const float4*)&i0[nb];
    float4 cc = *(const float4*)&ic[nb];
    v[0]=vv.x;  v[1]=vv.y;  v[2]=vv.z;  v[3]=vv.w;
    cur[0]=ii.x; cur[1]=ii.y; cur[2]=ii.z; cur[3]=ii.w;
    icr[0]=cc.x; icr[1]=cc.y; icr[2]=cc.z; icr[3]=cc.w;
  }
  // s0 = log(uniform(k_init,(n,)))-alpha; block c yields (u[c], u[c+1024])
#pragma unroll
  for (int k = 0; k < 4; ++k) {
    int j = nb + k;
    uint32_t x0 = (j < HALF_N) ? (uint32_t)j : (uint32_t)(j - HALF_N);
    uint32_t x1 = x0 + HALF_N;
    tf2x32(ki0, ki1, x0, x1);
    uint32_t bits = (j < HALF_N) ? x0 : x1;
    s[k] = xla_log(u01_from_bits(bits)) - 0.01f;
  }
  const float m0 = mu[0], m1 = mu[1];

  // ys[0] = y0   (12 consecutive floats per thread, 16B-aligned)
  {
    float4* yp = (float4*)(ys + (size_t)nb * 3);
    yp[0] = make_float4(v[0], cur[0], s[0], v[1]);
    yp[1] = make_float4(cur[1], s[1], v[2], cur[2]);
    yp[2] = make_float4(s[2], v[3], cur[3], s[3]);
  }

  __shared__ alignas(16) uint32_t red[2][8];
  const int wave = t >> 6;
  const int lane = t & 63;
  int nsp = 0;
  const bool use_sres = (sres != nullptr);
  const float* sp_ptr = use_sres ? (sres + nb) : nullptr;
  float* yrow = ys + (size_t)N_NEUR * 3 + (size_t)nb * 3;
  float tprev = ts[0];

  for (int step = 0; step < T - 1; ++step) {
    const float tnxt = ts[step + 1];
    const float dt = tnxt - tprev;
    tprev = tnxt;

    // prefetch reset values (data-independent, off critical path)
    float srp[4];
    if (use_sres) {
      float4 sv = *(const float4*)sp_ptr;
      srp[0]=sv.x; srp[1]=sv.y; srp[2]=sv.z; srp[3]=sv.w;
      sp_ptr += N_NEUR;
    }

    // y1 = y + dt*drift(y)
    float y1v[4], y1i[4], y1s[4];
    bool ev[4];
#pragma unroll
    for (int k = 0; k < 4; ++k) {
      float sp = softplus_xla(v[k]);
      float dv = m0 * ((cur[k] + icr[k]) - v[k]);
      float di = (-m1) * cur[k];
      y1v[k] = v[k] + dt * dv;
      y1i[k] = cur[k] + dt * di;
      y1s[k] = s[k] + dt * sp;
      ev[k] = (y1s[k] >= 0.0f);
    }

    // first spiking neuron: thread-local min index, then ballot+readlane,
    // then 8-entry LDS min across waves (single barrier, double-buffered)
    int lidx = 4;
    if (ev[3]) lidx = 3;
    if (ev[2]) lidx = 2;
    if (ev[1]) lidx = 1;
    if (ev[0]) lidx = 0;
    unsigned long long m = __ballot(lidx < 4);
    uint32_t wmin = 0xFFFFFFFFu;
    if (m) {
      int fl = __builtin_ctzll(m);
      wmin = (uint32_t)__builtin_amdgcn_readlane(nb + lidx, fl);
    }
    if (lane == 0) red[step & 1][wave] = wmin;
    __syncthreads();
    uint32_t e0;
    {
      const uint4* rp = (const uint4*)&red[step & 1][0];
      uint4 r0 = rp[0], r1 = rp[1];
      e0 = r0.x;
      e0 = r0.y < e0 ? r0.y : e0;
      e0 = r0.z < e0 ? r0.z : e0;
      e0 = r0.w < e0 ? r0.w : e0;
      e0 = r1.x < e0 ? r1.x : e0;
      e0 = r1.y < e0 ? r1.y : e0;
      e0 = r1.z < e0 ? r1.z : e0;
      e0 = r1.w < e0 ? r1.w : e0;
    }
    const bool has = (e0 != 0xFFFFFFFFu);

    float y2v[4], y2i[4], y2s[4];
    if (has) {
      uint32_t eu = (uint32_t)__builtin_amdgcn_readfirstlane((int)e0);
      float4 wv4 = *(const float4*)&w[(size_t)eu * N_NEUR + nb];
      float wv[4] = {wv4.x, wv4.y, wv4.z, wv4.w};
      float sr[4];
#pragma unroll
      for (int k = 0; k < 4; ++k) sr[k] = y1s[k];
      if (ev[0] | ev[1] | ev[2] | ev[3]) {
        if (use_sres) {
#pragma unroll
          for (int k = 0; k < 4; ++k) if (ev[k]) sr[k] = srp[k];
        } else {
          uint32_t f0 = 0u, f1 = (uint32_t)step;
          tf2x32(kt0, kt1, f0, f1);
#pragma unroll
          for (int k = 0; k < 4; ++k) {
            if (ev[k]) {
              int j = nb + k;
              uint32_t c0 = (j < HALF_N) ? (uint32_t)j : (uint32_t)(j - HALF_N);
              uint32_t c1 = c0 + HALF_N;
              tf2x32(f0, f1, c0, c1);
              uint32_t bits = (j < HALF_N) ? c0 : c1;
              sr[k] = xla_log(u01_from_bits(bits)) - 0.01f;
            }
          }
        }
      }
#pragma unroll
      for (int k = 0; k < 4; ++k) {
        y2v[k] = y1v[k] - (ev[k] ? 1.0f : 0.0f);
        y2i[k] = y1i[k] + wv[k];
        y2s[k] = sr[k];
      }
      if (nsp < MS) {
        if (t == 0) tev[nsp] = tnxt;
        float4* ye = (float4*)(yev + ((size_t)nsp * N_NEUR + nb) * 3);
        ye[0] = make_float4(y1v[0], y1i[0], y1s[0], y1v[1]);
        ye[1] = make_float4(y1i[1], y1s[1], y1v[2], y1i[2]);
        ye[2] = make_float4(y1s[2], y1v[3], y1i[3], y1s[3]);
        float4* ee = (float4*)(etv + (size_t)nsp * N_NEUR + nb);
        ee[0] = make_float4(ev[0] ? 1.0f : 0.0f, ev[1] ? 1.0f : 0.0f,
                            ev[2] ? 1.0f : 0.0f, ev[3] ? 1.0f : 0.0f);
      }
      nsp += 1;
    } else {
#pragma unroll
      for (int k = 0; k < 4; ++k) {
        y2v[k] = y1v[k]; y2i[k] = y1i[k]; y2s[k] = y1s[k];
      }
    }

    // ys[step+1] : 3x dwordx4
    {
      float4* yp = (float4*)yrow;
      yp[0] = make_float4(y2v[0], y2i[0], y2s[0], y2v[1]);
      yp[1] = make_float4(y2i[1], y2s[1], y2v[2], y2i[2]);
      yp[2] = make_float4(y2s[2], y2v[3], y2i[3], y2s[3]);
      yrow += (size_t)N_NEUR * 3;
    }

#pragma unroll
    for (int k = 0; k < 4; ++k) {
      v[k] = y2v[k]; cur[k] = y2i[k]; s[k] = y2s[k];
    }
  }

  if (t == 0) nspp[0] = (float)nsp;
}

extern "C" void kernel_launch(void* const* d_in, const int* in_sizes, int n_in,
                              void* d_out, int out_size, void* d_ws, size_t ws_size,
                              hipStream_t stream) {
  const float* ts = (const float*)d_in[0];
  const float* v0 = (const float*)d_in[1];
  const float* i0 = (const float*)d_in[2];
  const float* ic = (const float*)d_in[3];
  const float* w  = (const float*)d_in[4];
  const float* mu = (const float*)d_in[5];
  const int* seed = (const int*)d_in[6];

  const int T = in_sizes[0];      // 4000
  const int N = in_sizes[1];      // 2048
  long long rem = (long long)out_size - (long long)T * N * 3 - 1;
  int MS = (int)(rem / (1 + 4 * (long long)N));
  if (MS <= 0) MS = 512;

  size_t inf_base = (size_t)T * N * 3;
  size_t inf_cnt  = (size_t)MS + (size_t)MS * N * 3;
  size_t zero_cnt = (size_t)MS * N;
  snn_init<<<dim3(512), dim3(256), 0, stream>>>((float*)d_out, inf_base, inf_cnt, zero_cnt);

  const float* sres = nullptr;
  size_t need = (size_t)(T - 1) * (size_t)N * sizeof(float);
  if (ws_size >= need) {
    snn_pre<<<dim3(T - 1), dim3(1024), 0, stream>>>(seed, (float*)d_ws);
    sres = (const float*)d_ws;
  }

  snn_sim<<<dim3(1), dim3(512), 0, stream>>>(ts, v0, i0, ic, w, mu, seed, sres,
                                             (float*)d_out, T, MS);
}

// Round 3
// 4211.777 us; speedup vs baseline: 1.1116x; 1.1116x over previous
//
#include <hip/hip_runtime.h>
#include <stdint.h>

// ====== variant switches for XLA:CPU transcendental reconstruction ======
// (verified bit-exact in round 1 — DO NOT change the math)
#define XLA_LOG_TAIL_A 1
#define XLA_USE_FMA    0

#if XLA_USE_FMA
#define MADD(a,b,c) __builtin_fmaf((a),(b),(c))
#else
#define MADD(a,b,c) ((a)*(b)+(c))
#endif

#define N_NEUR 2048
#define HALF_N 1024

// ---------------- threefry2x32 (exact JAX primitive) ----------------
__device__ __forceinline__ uint32_t rotl32(uint32_t x, int r) {
  return (x << r) | (x >> (32 - r));
}

__device__ __forceinline__ void tf2x32(uint32_t k0, uint32_t k1,
                                       uint32_t& x0, uint32_t& x1) {
  const uint32_t k2 = k0 ^ k1 ^ 0x1BD11BDAu;
  x0 += k0; x1 += k1;
#define TF_R(r) { x0 += x1; x1 = rotl32(x1, r); x1 ^= x0; }
  TF_R(13) TF_R(15) TF_R(26) TF_R(6)
  x0 += k1; x1 += k2 + 1u;
  TF_R(17) TF_R(29) TF_R(16) TF_R(24)
  x0 += k2; x1 += k0 + 2u;
  TF_R(13) TF_R(15) TF_R(26) TF_R(6)
  x0 += k0; x1 += k1 + 3u;
  TF_R(17) TF_R(29) TF_R(16) TF_R(24)
  x0 += k1; x1 += k2 + 4u;
  TF_R(13) TF_R(15) TF_R(26) TF_R(6)
  x0 += k2; x1 += k0 + 5u;
#undef TF_R
}

__device__ __forceinline__ float u01_from_bits(uint32_t bits) {
#pragma clang fp contract(off)
  float f = __uint_as_float((bits >> 9) | 0x3f800000u);
  return f - 1.0f;
}

// ---------------- XLA:CPU GenerateVF32Log (Cephes, Estrin poly) ----------------
__device__ __forceinline__ float xla_log(float xin) {
#pragma clang fp contract(off)
  float t0 = fmaxf(xin, __uint_as_float(0x00800000u));
  uint32_t bits = __float_as_uint(t0);
  int em = (int)(bits >> 23) - 127;
  t0 = __uint_as_float((bits & 0x807fffffu) | 0x3f000000u);
  float e = 1.0f + (float)em;
  const bool mlt = t0 < (float)0.707106781186547524;
  float tmp1 = mlt ? t0 : 0.0f;
  t0 = t0 - 1.0f;
  e = e - (mlt ? 1.0f : 0.0f);
  t0 = t0 + tmp1;
  float x2 = t0 * t0;
  float x3 = x2 * t0;
  float y  = MADD(t0, (float)7.0376836292E-2, (float)-1.1514610310E-1);
  float ya = MADD(t0, (float)-1.2420140846E-1, (float)1.4249322787E-1);
  float yb = MADD(t0, (float)2.0000714765E-1, (float)-2.4999993993E-1);
  y  = MADD(y,  t0, (float)1.1676998740E-1);
  ya = MADD(ya, t0, (float)-1.6668057665E-1);
  yb = MADD(yb, t0, (float)3.3333331174E-1);
  y  = MADD(y, x3, ya);
  y  = MADD(y, x3, yb);
  y  = y * x3;
  float ey1 = e * (float)-2.12194440e-4;
  float hx2 = x2 * 0.5f;
  y = y + ey1;
  t0 = t0 - hx2;
  float ey2 = e * (float)0.693359375;
#if XLA_LOG_TAIL_A
  t0 = t0 + y;
  t0 = t0 + ey2;
#else
  t0 = t0 + ey2;
  t0 = t0 + y;
#endif
  if (xin == 0.0f) return -__builtin_inff();
  return t0;
}

// ---------------- XLA:CPU GenerateVF32Exp (old Cephes structure) ----------------
__device__ __forceinline__ float xla_exp(float xin) {
#pragma clang fp contract(off)
  float x = fmaxf(xin, (float)-88.3762626647949);
  x = fminf(x, (float)88.3762626647950);
  float fx = floorf(MADD(x, (float)1.44269504088896341, 0.5f));
  float tmp = (float)0.693359375 * fx;
  float z = (float)-2.12194440e-4 * fx;
  x = x - tmp;
  x = x - z;
  z = x * x;
  float y = MADD(x, (float)1.9875691500E-4, (float)1.3981999507E-3);
  y = MADD(y, x, (float)8.3334519073E-3);
  y = MADD(y, x, (float)4.1665795894E-2);
  y = MADD(y, x, (float)1.6666665459E-1);
  y = MADD(y, x, (float)5.0000001201E-1);
  y = MADD(y, z, x);
  y = 1.0f + y;
  int n = (int)fx;
  float p2n = __uint_as_float((uint32_t)(n + 127) << 23);
  return fmaxf(y * p2n, xin);
}

__device__ __forceinline__ float xla_log1p(float x) {
#pragma clang fp contract(off)
  float fl = xla_log(x + 1.0f);
  float fs = ((-0.5f * x) + 1.0f) * x;
  return (fabsf(x) < (float)1e-4) ? fs : fl;
}

// jax.nn.softplus(v) = max(v,0) + log1p(exp(-|v|))
__device__ __forceinline__ float softplus_xla(float v) {
#pragma clang fp contract(off)
  // exact shortcut: for v>=16, exp(-v)<=1.13e-7 < ulp(v)/2 -> sum rounds to v
  if (v >= 16.0f) return v;
  float a = fabsf(v);
  float ex = xla_exp(-a);
  float lp = xla_log1p(ex);
  return fmaxf(v, 0.0f) + lp;
}

// ---------------- init: tevents/yevents = +inf, event_types = 0 ----------------
__global__ void snn_init(float* __restrict__ out, size_t inf_base,
                         size_t inf_cnt, size_t zero_cnt) {
  size_t i = (size_t)blockIdx.x * blockDim.x + threadIdx.x;
  size_t stride = (size_t)gridDim.x * blockDim.x;
  size_t total = inf_cnt + zero_cnt;
  for (size_t k = i; k < total; k += stride) {
    out[inf_base + k] = (k < inf_cnt) ? __builtin_inff() : 0.0f;
  }
}

// ---------------- precompute s_reset[step][j] = log(u)-alpha into d_ws ---------
__global__ __launch_bounds__(1024)
void snn_pre(const int* __restrict__ seedp, float* __restrict__ sres) {
#pragma clang fp contract(off)
  const int step = blockIdx.x;       // 0..T-2
  const int t = threadIdx.x;
  uint32_t seed = (uint32_t)seedp[0];
  uint32_t a0 = 0u, a1 = 2u; tf2x32(0u, seed, a0, a1);
  uint32_t b0 = 1u, b1 = 3u; tf2x32(0u, seed, b0, b1);
  uint32_t f0 = 0u, f1 = (uint32_t)step; tf2x32(a1, b1, f0, f1);
  uint32_t d0 = (uint32_t)t, d1 = (uint32_t)(t + HALF_N);
  tf2x32(f0, f1, d0, d1);
  float srA = xla_log(u01_from_bits(d0)) - 0.01f;
  float srB = xla_log(u01_from_bits(d1)) - 0.01f;
  sres[(size_t)step * N_NEUR + t] = srA;
  sres[(size_t)step * N_NEUR + HALF_N + t] = srB;
}

// ------- the sequential scan: 1 block, 1024 threads, 2 contiguous neurons -----
// Software-pipelined: the w-row load issued at step k is consumed at step k+1
// (i carried as pre-w "pending" y1i); ts prefetched 2 ahead; sres 1 ahead.
__global__ __launch_bounds__(1024, 1)
void snn_sim(const float* __restrict__ ts, const float* __restrict__ v0,
             const float* __restrict__ i0, const float* __restrict__ ic,
             const float* __restrict__ w, const float* __restrict__ mu,
             const int* __restrict__ seedp, const float* __restrict__ sres,
             float* __restrict__ out, int T, int MS) {
#pragma clang fp contract(off)
  const int t = threadIdx.x;
  const int nb = t * 2;                 // 2 contiguous neurons nb, nb+1

  float* ys   = out;                                     // [T][N][3]
  float* tev  = out + (size_t)T * N_NEUR * 3;            // [MS]
  float* yev  = tev + (size_t)MS;                        // [MS][N][3]
  float* etv  = yev + (size_t)MS * N_NEUR * 3;           // [MS][N]
  float* nspp = etv + (size_t)MS * N_NEUR;               // [1]

  // keys: key=(0,seed); split -> k_init (first cipher words), k_trans (second)
  uint32_t seed = (uint32_t)seedp[0];
  uint32_t a0 = 0u, a1 = 2u; tf2x32(0u, seed, a0, a1);
  uint32_t b0 = 1u, b1 = 3u; tf2x32(0u, seed, b0, b1);
  const uint32_t ki0 = a0, ki1 = b0;   // k_init
  const uint32_t kt0 = a1, kt1 = b1;   // k_trans

  float v[2], ipd[2], s[2], icr[2];    // ipd = pending (pre-w) i
  { float2 x = *(const float2*)&v0[nb]; v[0] = x.x; v[1] = x.y; }
  { float2 x = *(const float2*)&i0[nb]; ipd[0] = x.x; ipd[1] = x.y; }
  { float2 x = *(const float2*)&ic[nb]; icr[0] = x.x; icr[1] = x.y; }
  // s0: uniform(k_init,(2048,)) block c -> (word0=u[c], word1=u[c+1024])
#pragma unroll
  for (int k2 = 0; k2 < 2; ++k2) {
    int j = nb + k2;
    uint32_t c0 = (j < HALF_N) ? (uint32_t)j : (uint32_t)(j - HALF_N);
    uint32_t c1 = c0 + HALF_N;
    tf2x32(ki0, ki1, c0, c1);
    s[k2] = xla_log(u01_from_bits((j < HALF_N) ? c0 : c1)) - 0.01f;
  }
  const float m0 = mu[0], m1 = mu[1];

  __shared__ alignas(16) uint32_t red[2][16];
  const int wave = t >> 6;
  const int lane = t & 63;
  int nsp = 0;
  bool hasPrev = false;
  float wvp[2] = {0.0f, 0.0f};
  const bool use_sres = (sres != nullptr);

  // pipelined scalars
  float tprev = ts[0], tnxt = ts[1];
  float srp[2] = {0.0f, 0.0f};
  if (use_sres) { float2 x = *(const float2*)(sres + nb); srp[0] = x.x; srp[1] = x.y; }
  float* yrow = ys + (size_t)nb * 3;

  for (int k = 0; k < T - 1; ++k) {
    const float dt = tnxt - tprev;
    // prefetch ts[k+2] and sres row k+1 (consumed next iteration)
    float tsn = ts[(k + 2 < T) ? (k + 2) : (T - 1)];
    float srn0 = 0.0f, srn1 = 0.0f;
    if (use_sres && (k + 1 < T - 1)) {
      float2 x = *(const float2*)(sres + (size_t)(k + 1) * N_NEUR + nb);
      srn0 = x.x; srn1 = x.y;
    }

    // ---- event chain: needs only v, s (lane-local)
    float sp0 = softplus_xla(v[0]);
    float sp1 = softplus_xla(v[1]);
    float y1s0 = s[0] + dt * sp0;
    float y1s1 = s[1] + dt * sp1;
    const bool ev0 = (y1s0 >= 0.0f);
    const bool ev1 = (y1s1 >= 0.0f);
    int lidx = ev0 ? 0 : (ev1 ? 1 : 2);
    unsigned long long mm = __ballot(lidx < 2);
    uint32_t wmin = 0xFFFFFFFFu;
    if (mm) {
      int fl = __builtin_ctzll(mm);
      wmin = (uint32_t)__builtin_amdgcn_readlane(nb + lidx, fl);
    }
    if (lane == 0) red[k & 1][wave] = wmin;

    // ---- resolve i_k from pending (consumes w row issued at step k-1)
    float i0r = hasPrev ? (ipd[0] + wvp[0]) : ipd[0];
    float i1r = hasPrev ? (ipd[1] + wvp[1]) : ipd[1];

    // ---- y1v, y1i
    float dv0 = m0 * ((i0r + icr[0]) - v[0]);
    float dv1 = m0 * ((i1r + icr[1]) - v[1]);
    float y1v0 = v[0] + dt * dv0;
    float y1v1 = v[1] + dt * dv1;
    float y1i0 = i0r + dt * ((-m1) * i0r);
    float y1i1 = i1r + dt * ((-m1) * i1r);

    // ---- store ys row k = committed state (v_k, i_k, s_k)
    ((float2*)yrow)[0] = make_float2(v[0], i0r);
    ((float2*)yrow)[1] = make_float2(s[0], v[1]);
    ((float2*)yrow)[2] = make_float2(i1r, s[1]);
    yrow += (size_t)N_NEUR * 3;

    __syncthreads();

    // ---- block reduce (off the carried path) + issue next w row load
    uint32_t e0;
    {
      const uint4* rp = (const uint4*)&red[k & 1][0];
      uint4 r0 = rp[0], r1 = rp[1], r2 = rp[2], r3 = rp[3];
      uint32_t a = r0.x < r0.y ? r0.x : r0.y;
      uint32_t b = r0.z < r0.w ? r0.z : r0.w;
      uint32_t c = r1.x < r1.y ? r1.x : r1.y;
      uint32_t d = r1.z < r1.w ? r1.z : r1.w;
      uint32_t e = r2.x < r2.y ? r2.x : r2.y;
      uint32_t f = r2.z < r2.w ? r2.z : r2.w;
      uint32_t g = r3.x < r3.y ? r3.x : r3.y;
      uint32_t h = r3.z < r3.w ? r3.z : r3.w;
      a = a < b ? a : b;  c = c < d ? c : d;
      e = e < f ? e : f;  g = g < h ? g : h;
      a = a < c ? a : c;  e = e < g ? e : g;
      e0 = a < e ? a : e;
    }
    e0 = (uint32_t)__builtin_amdgcn_readfirstlane((int)e0);
    const bool has = (e0 != 0xFFFFFFFFu);
    float wn0 = 0.0f, wn1 = 0.0f;
    if (has) {
      float2 x = *(const float2*)&w[((size_t)e0 << 11) + nb];
      wn0 = x.x; wn1 = x.y;
    }

    // ---- recording (uses y1, lane-local ev)
    if (has) {
      if (nsp < MS) {
        if (t == 0) tev[nsp] = tnxt;
        float* ye = yev + ((size_t)nsp * N_NEUR + nb) * 3;
        ((float2*)ye)[0] = make_float2(y1v0, y1i0);
        ((float2*)ye)[1] = make_float2(y1s0, y1v1);
        ((float2*)ye)[2] = make_float2(y1i1, y1s1);
        *(float2*)(etv + (size_t)nsp * N_NEUR + nb) =
            make_float2(ev0 ? 1.0f : 0.0f, ev1 ? 1.0f : 0.0f);
      }
      nsp += 1;
    }

    // ---- finalize local state (ev ⊆ has: v,s resets are lane-local)
    float sr0 = y1s0, sr1 = y1s1;
    if (use_sres) {
      if (ev0) sr0 = srp[0];
      if (ev1) sr1 = srp[1];
    } else if (ev0 | ev1) {
      uint32_t f0 = 0u, f1 = (uint32_t)k;
      tf2x32(kt0, kt1, f0, f1);
#pragma unroll
      for (int k2 = 0; k2 < 2; ++k2) {
        if (k2 == 0 ? ev0 : ev1) {
          int j = nb + k2;
          uint32_t c0 = (j < HALF_N) ? (uint32_t)j : (uint32_t)(j - HALF_N);
          uint32_t c1 = c0 + HALF_N;
          tf2x32(f0, f1, c0, c1);
          float r = xla_log(u01_from_bits((j < HALF_N) ? c0 : c1)) - 0.01f;
          if (k2 == 0) sr0 = r; else sr1 = r;
        }
      }
    }
    v[0] = y1v0 - (ev0 ? 1.0f : 0.0f);
    v[1] = y1v1 - (ev1 ? 1.0f : 0.0f);
    s[0] = sr0;
    s[1] = sr1;
    ipd[0] = y1i0;
    ipd[1] = y1i1;
    wvp[0] = wn0;
    wvp[1] = wn1;
    hasPrev = has;
    srp[0] = srn0;
    srp[1] = srn1;
    tprev = tnxt;
    tnxt = tsn;
  }

  // final row T-1: resolve pending i and store
  float i0f = hasPrev ? (ipd[0] + wvp[0]) : ipd[0];
  float i1f = hasPrev ? (ipd[1] + wvp[1]) : ipd[1];
  ((float2*)yrow)[0] = make_float2(v[0], i0f);
  ((float2*)yrow)[1] = make_float2(s[0], v[1]);
  ((float2*)yrow)[2] = make_float2(i1f, s[1]);
  if (t == 0) nspp[0] = (float)nsp;
}

extern "C" void kernel_launch(void* const* d_in, const int* in_sizes, int n_in,
                              void* d_out, int out_size, void* d_ws, size_t ws_size,
                              hipStream_t stream) {
  const float* ts = (const float*)d_in[0];
  const float* v0 = (const float*)d_in[1];
  const float* i0 = (const float*)d_in[2];
  const float* ic = (const float*)d_in[3];
  const float* w  = (const float*)d_in[4];
  const float* mu = (const float*)d_in[5];
  const int* seed = (const int*)d_in[6];

  const int T = in_sizes[0];      // 4000
  const int N = in_sizes[1];      // 2048
  long long rem = (long long)out_size - (long long)T * N * 3 - 1;
  int MS = (int)(rem / (1 + 4 * (long long)N));
  if (MS <= 0) MS = 512;

  size_t inf_base = (size_t)T * N * 3;
  size_t inf_cnt  = (size_t)MS + (size_t)MS * N * 3;
  size_t zero_cnt = (size_t)MS * N;
  snn_init<<<dim3(512), dim3(256), 0, stream>>>((float*)d_out, inf_base, inf_cnt, zero_cnt);

  const float* sres = nullptr;
  size_t need = (size_t)(T - 1) * (size_t)N * sizeof(float);
  if (ws_size >= need) {
    snn_pre<<<dim3(T - 1), dim3(1024), 0, stream>>>(seed, (float*)d_ws);
    sres = (const float*)d_ws;
  }

  snn_sim<<<dim3(1), dim3(1024), 0, stream>>>(ts, v0, i0, ic, w, mu, seed, sres,
                                              (float*)d_out, T, MS);
}